// Round 14
// baseline (1593.801 us; speedup 1.0000x reference)
//
#include <hip/hip_runtime.h>
#include <hip/hip_cooperative_groups.h>
#include <math.h>

namespace coop = cooperative_groups;

#define H 6
#define DH 64
#define D 384
#define L 16
#define WSZ ((size_t)(D) * (D))
#define RSZ ((size_t)(H) * (DH) * (DH))

typedef __attribute__((ext_vector_type(8))) short short8;
typedef __attribute__((ext_vector_type(4))) float f32x4;
typedef unsigned int uint_;

__device__ __forceinline__ float bf2f(unsigned short u) {
  union { unsigned int i; float f; } x; x.i = ((unsigned int)u) << 16; return x.f;
}
__device__ __forceinline__ unsigned short f2bf(float f) {
  unsigned int x = __float_as_uint(f);
  x = x + 0x7fffu + ((x >> 16) & 1u);
  return (unsigned short)(x >> 16);
}
__device__ __forceinline__ float blo(unsigned int u) { return __uint_as_float(u << 16); }
__device__ __forceinline__ float bhi(unsigned int u) { return __uint_as_float(u & 0xffff0000u); }
__device__ __forceinline__ float geluf(float x) {
  return 0.5f * x * (1.0f + erff(x * 0.70710678118654752f));
}

__global__ void zero_int_kernel(int* p, long n) {
  long i = (long)blockIdx.x * blockDim.x + threadIdx.x;
  long stride = (long)gridDim.x * blockDim.x;
  for (; i < n; i += stride) p[i] = 0;
}

// ---- fused pool+count+prep launch (R12-proven), 512 threads/block, union LDS ----
__global__ __launch_bounds__(512) void poolprep_kernel(
    const float* __restrict__ tokM, const int* __restrict__ idsM,
    unsigned short* __restrict__ outM, int NM,
    const float* __restrict__ tokC, const int* __restrict__ idsC,
    unsigned short* __restrict__ outC, int NPOOL,
    const int* __restrict__ dc0, const int* __restrict__ dc1,
    int* __restrict__ deg0, int* __restrict__ deg1, int E, int CH,
    const float* __restrict__ lin_W, const float* __restrict__ kW,
    const float* __restrict__ qW, const float* __restrict__ vW,
    const float* __restrict__ aW, const float* __restrict__ a_rel,
    const float* __restrict__ m_rel, const float* __restrict__ p_rel,
    const float* __restrict__ kb, const float* __restrict__ qb,
    const float* __restrict__ vb,
    unsigned short* __restrict__ wbuf, float* __restrict__ bbuf) {
  __shared__ __align__(16) char smem[16768];
  int t = threadIdx.x;
  if ((int)blockIdx.x < NPOOL) {
    {
      int e = blockIdx.x * CH + t;
      if (t < CH && e < 2 * E) {
        if (e < E) atomicAdd(&deg0[dc0[e]], 1);
        else atomicAdd(&deg1[dc1[e - E]], 1);
      }
    }
    float4 (*part)[96] = (float4(*)[96])smem;
    float* wpart = (float*)(smem + 6144);
    int n = blockIdx.x;
    const float* tok; const int* ids; unsigned short* out;
    if (n < NM) { tok = tokM; ids = idsM; out = outM; }
    else { n -= NM; tok = tokC; ids = idsC; out = outC; }
    int rg = t / 96, c4 = t % 96;
    const float4* tp = (const float4*)(tok + (size_t)n * L * D);
    const int* ip = ids + (size_t)n * L;
    int cnt = 0;
#pragma unroll
    for (int l = 0; l < L; ++l) cnt += (ip[l] > 0);
    float4 s = {0.f, 0.f, 0.f, 0.f};
    if (t < 384) {
#pragma unroll
      for (int li = 0; li < 4; ++li) {
        int l = rg + li * 4;
        if (ip[l] > 0) {
          float4 v = tp[l * 96 + c4];
          s.x += v.x; s.y += v.y; s.z += v.z; s.w += v.w;
        }
      }
      part[rg][c4] = s;
    }
    __syncthreads();
    float4 m4 = {0.f, 0.f, 0.f, 0.f};
    float dot = 0.f;
    float inv_cnt = 1.0f / fmaxf((float)cnt, 1e-9f);
    if (t < 96) {
      float4 a = part[0][t], b = part[1][t], c = part[2][t], d2 = part[3][t];
      m4.x = (a.x + b.x + c.x + d2.x) * inv_cnt;
      m4.y = (a.y + b.y + c.y + d2.y) * inv_cnt;
      m4.z = (a.z + b.z + c.z + d2.z) * inv_cnt;
      m4.w = (a.w + b.w + c.w + d2.w) * inv_cnt;
      dot = m4.x * m4.x + m4.y * m4.y + m4.z * m4.z + m4.w * m4.w;
    }
#pragma unroll
    for (int o = 32; o; o >>= 1) dot += __shfl_down(dot, o);
    if ((t & 63) == 0) wpart[t >> 6] = dot;
    __syncthreads();
    float tot = 0.f;
#pragma unroll
    for (int i = 0; i < 8; ++i) tot += wpart[i];
    float inv = 1.0f / fmaxf(sqrtf(tot), 1e-12f);
    if (t < 96) {
      uint2 o;
      o.x = (uint_)f2bf(m4.x * inv) | ((uint_)f2bf(m4.y * inv) << 16);
      o.y = (uint_)f2bf(m4.z * inv) | ((uint_)f2bf(m4.w * inv) << 16);
      ((uint2*)(out + (size_t)n * D))[t] = o;
    }
    return;
  }
  int q = blockIdx.x - NPOOL;
  if (q >= 14 * 144) {
    int i = (q - 14 * 144) * 512 + t;
    if (i >= 3456) return;
    int gemm, col;
    if (i < 1152) { gemm = 0; col = i; }
    else if (i < 2304) { gemm = 1; col = i - 1152; }
    else if (i < 2688) { gemm = 2; col = i - 2304; }
    else { gemm = 3; col = i - 2688; }
    int sec = col / D, j = col % D, h = j >> 6, rr = j & 63;
    float out = 0.f;
    if (gemm == 0) {
      if (sec == 0) out = kb[j];
      else if (sec == 1) {
        const float* R = a_rel + (size_t)h * 4096 + (size_t)rr * 64;
        float s = 0.f; for (int f = 0; f < 64; ++f) s += qb[h * 64 + f] * R[f];
        out = s * p_rel[h] * 0.125f;
      } else {
        const float* Mm = m_rel + RSZ + (size_t)h * 4096;
        float s = 0.f; for (int d = 0; d < 64; ++d) s += vb[h * 64 + d] * Mm[d * 64 + rr]; out = s;
      }
    } else if (gemm == 1) {
      if (sec == 0) out = kb[D + j];
      else if (sec == 1) {
        const float* R = a_rel + RSZ + (size_t)h * 4096 + (size_t)rr * 64;
        float s = 0.f; for (int f = 0; f < 64; ++f) s += qb[D + h * 64 + f] * R[f];
        out = s * p_rel[H + h] * 0.125f;
      } else {
        const float* Mm = m_rel + (size_t)h * 4096;
        float s = 0.f; for (int d = 0; d < 64; ++d) s += vb[D + h * 64 + d] * Mm[d * 64 + rr]; out = s;
      }
    } else if (gemm == 2) {
      const float* R = a_rel + 2 * RSZ + (size_t)h * 4096 + (size_t)rr * 64;
      float s = 0.f; for (int f = 0; f < 64; ++f) s += qb[2 * D + h * 64 + f] * R[f];
      out = s * p_rel[2 * H + h] * 0.125f;
    } else {
      if (sec == 0) out = kb[3 * D + j];
      else {
        const float* Mm = m_rel + 2 * RSZ + (size_t)h * 4096;
        float s = 0.f; for (int d = 0; d < 64; ++d) s += vb[3 * D + h * 64 + d] * Mm[d * 64 + rr]; out = s;
      }
    }
    bbuf[i] = out;
    return;
  }
  int z = q / 144;
  int r = q % 144;
  int px = r % 12, py = r / 12;
  int tx = t & 31, ty16 = t >> 5;
  const float* src; const float* rel = nullptr; const float* prl = nullptr; int type = 0;
  switch (z) {
    case 0: src = lin_W; break;
    case 1: src = lin_W + WSZ; break;
    case 2: src = kW; break;
    case 3: type = 1; src = qW; rel = a_rel; prl = p_rel; break;
    case 4: type = 2; src = vW; rel = m_rel + RSZ; break;
    case 5: src = kW + WSZ; break;
    case 6: type = 1; src = qW + WSZ; rel = a_rel + RSZ; prl = p_rel + H; break;
    case 7: type = 2; src = vW + WSZ; rel = m_rel; break;
    case 8: type = 1; src = qW + 2 * WSZ; rel = a_rel + 2 * RSZ; prl = p_rel + 2 * H; break;
    case 9: src = kW + 3 * WSZ; break;
    case 10: type = 2; src = vW + 3 * WSZ; rel = m_rel + 2 * RSZ; break;
    case 11: src = aW; break;
    case 12: src = aW + WSZ; break;
    default: src = aW + 2 * WSZ; break;
  }
  unsigned short* dst = wbuf + (size_t)z * WSZ;
  int bx = px * 32;
  int by = py * 32;
  if (type == 0) {
    float (*tile)[33] = (float(*)[33])smem;
#pragma unroll
    for (int s = 0; s < 2; ++s) {
      int r2 = ty16 + s * 16;
      tile[r2][tx] = src[(size_t)(bx + r2) * D + by + tx];
    }
    __syncthreads();
#pragma unroll
    for (int s = 0; s < 2; ++s) {
      int ny = ty16 + s * 16;
      dst[(size_t)(by + ny) * D + bx + tx] = f2bf(tile[tx][ny]);
    }
  } else if (type == 1) {
    float (*Wt_)[65] = (float(*)[65])smem;
    float (*Rt)[65] = (float(*)[65])(smem + 8320);
    int h = by >> 6, d0 = by & 63;
    float sc = prl[h] * 0.125f;
#pragma unroll
    for (int i = 0; i < 4; ++i) {
      int idx = t + i * 512;
      int wr = idx >> 6, wc = idx & 63;
      Wt_[wr][wc] = src[(size_t)(bx + wr) * D + h * 64 + wc];
      Rt[wr][wc] = rel[(size_t)h * 4096 + (size_t)(d0 + wr) * 64 + wc];
    }
    __syncthreads();
#pragma unroll
    for (int s = 0; s < 2; ++s) {
      int ny = ty16 + s * 16;
      float acc = 0.f;
#pragma unroll 16
      for (int f = 0; f < 64; ++f) acc += Wt_[tx][f] * Rt[ny][f];
      dst[(size_t)(by + ny) * D + bx + tx] = f2bf(acc * sc);
    }
  } else {
    float (*Wt2)[65] = (float(*)[65])smem;
    float (*Mt)[33] = (float(*)[33])(smem + 8320);
    int h = by >> 6, f0 = by & 63;
#pragma unroll
    for (int i = 0; i < 4; ++i) {
      int idx = t + i * 512;
      int wr = idx >> 6, wc = idx & 63;
      Wt2[wr][wc] = src[(size_t)(bx + wr) * D + h * 64 + wc];
      int dr = idx >> 5, fc = idx & 31;
      Mt[dr][fc] = rel[(size_t)h * 4096 + (size_t)dr * 64 + f0 + fc];
    }
    __syncthreads();
#pragma unroll
    for (int s = 0; s < 2; ++s) {
      int ny = ty16 + s * 16;
      float acc = 0.f;
#pragma unroll 16
      for (int d = 0; d < 64; ++d) acc += Wt2[tx][d] * Mt[d][ny];
      dst[(size_t)(by + ny) * D + bx + tx] = f2bf(acc);
    }
  }
}

// wave-shuffle scan
__global__ void scan2_kernel(const int* __restrict__ deg0, int* __restrict__ off0, int N0,
                             const int* __restrict__ deg1, int* __restrict__ off1, int N1) {
  const int* deg = blockIdx.x ? deg1 : deg0;
  int* off = blockIdx.x ? off1 : off0;
  int N = blockIdx.x ? N1 : N0;
  __shared__ int wsum[16];
  __shared__ int carrySh;
  int tid = threadIdx.x;
  int lane = tid & 63, wid = tid >> 6;
  if (tid == 0) carrySh = 0;
  __syncthreads();
  for (int base = 0; base < N; base += 1024) {
    int i = base + tid;
    int v = (i < N) ? deg[i] : 0;
    int s = v;
#pragma unroll
    for (int o = 1; o < 64; o <<= 1) {
      int t2 = __shfl_up(s, o);
      if (lane >= o) s += t2;
    }
    if (lane == 63) wsum[wid] = s;
    __syncthreads();
    int wpre = 0;
    for (int j = 0; j < wid; ++j) wpre += wsum[j];
    int c = carrySh;
    if (i < N) off[i] = c + wpre + s - v;
    __syncthreads();
    if (tid == 1023) carrySh = c + wpre + s;
    __syncthreads();
  }
  if (tid == 0) off[N] = carrySh;
}

// ---------------- shared device pieces (mega + fallback) ----------------
struct GP {
  const unsigned short* A;
  const unsigned short* Wt;
  const float* bias;
  float* Cf;
  unsigned short* Cb;
  const unsigned short* xold;
  const float* skipPtr;
  int M, N, cpitch, relu;
};
struct ScatP {
  const int *d0, *s0, *off0;
  int *cur0, *el0;
  const int *d1, *s1, *off1;
  int *cur1, *el1;
  int E;
};

__device__ void gemm_tile(const GP& p, int bm, int bn) {
  __shared__ __align__(16) unsigned short As[2][128 * 64];
  __shared__ __align__(16) unsigned short Bs[2][128 * 64];
  const int tid = threadIdx.x;
  const int w = tid >> 6, lane = tid & 63;

  auto stage = [&](int t, int buf) {
#pragma unroll
    for (int i = 0; i < 4; ++i) {
      int cid = (w * 4 + i) * 64 + lane;
      int row = cid >> 3;
      int cg2 = (cid & 7) ^ (row & 7);
      int grow = bm + row;
      if (grow >= p.M) grow = p.M - 1;
      const unsigned short* gp = p.A + (size_t)grow * D + t * 64 + cg2 * 8;
      __builtin_amdgcn_global_load_lds((const __attribute__((address_space(1))) void*)gp,
                                       (__attribute__((address_space(3))) void*)&As[buf][(w * 4 + i) * 512],
                                       16, 0, 0);
    }
#pragma unroll
    for (int i = 0; i < 4; ++i) {
      int cid = (w * 4 + i) * 64 + lane;
      int row = cid >> 3;
      int cg2 = (cid & 7) ^ (row & 7);
      const unsigned short* gp = p.Wt + (size_t)(bn + row) * D + t * 64 + cg2 * 8;
      __builtin_amdgcn_global_load_lds((const __attribute__((address_space(1))) void*)gp,
                                       (__attribute__((address_space(3))) void*)&Bs[buf][(w * 4 + i) * 512],
                                       16, 0, 0);
    }
  };

  stage(0, 0);
  __syncthreads();

  const int wr = w >> 1, wc = w & 1;
  const int la = lane & 15, hi = lane >> 4;
  f32x4 acc[4][4] = {};

  for (int t = 0; t < 6; ++t) {
    if (t < 5) stage(t + 1, (t + 1) & 1);
    const unsigned short* Ab = As[t & 1];
    const unsigned short* Bb = Bs[t & 1];
#pragma unroll
    for (int ks = 0; ks < 2; ++ks) {
      int c = ks * 4 + hi;
      short8 af[4], bfr[4];
#pragma unroll
      for (int mi = 0; mi < 4; ++mi) {
        int row = wr * 64 + mi * 16 + la;
        af[mi] = *(const short8*)&As[t & 1][row * 64 + ((c ^ (row & 7)) * 8)];
      }
#pragma unroll
      for (int n = 0; n < 4; ++n) {
        int col = wc * 64 + n * 16 + la;
        bfr[n] = *(const short8*)&Bb[col * 64 + ((c ^ (col & 7)) * 8)];
      }
#pragma unroll
      for (int mi = 0; mi < 4; ++mi)
#pragma unroll
        for (int n = 0; n < 4; ++n)
          acc[mi][n] = __builtin_amdgcn_mfma_f32_16x16x32_bf16(af[mi], bfr[n], acc[mi][n], 0, 0, 0);
    }
    __syncthreads();
  }

  float sa = 0.f;
  if (p.xold) sa = 1.0f / (1.0f + __expf(-*p.skipPtr));
#pragma unroll
  for (int mi = 0; mi < 4; ++mi) {
#pragma unroll
    for (int n = 0; n < 4; ++n) {
#pragma unroll
      for (int r = 0; r < 4; ++r) {
        int row = bm + wr * 64 + mi * 16 + hi * 4 + r;
        int col = bn + wc * 64 + n * 16 + la;
        if (row >= p.M) continue;
        float v = acc[mi][n][r] + p.bias[col];
        if (p.relu) v = fmaxf(v, 0.f);
        if (p.xold) v = sa * v + (1.0f - sa) * bf2f(p.xold[(size_t)row * D + col]);
        if (p.Cf) p.Cf[(size_t)row * p.cpitch + col] = v;
        if (p.Cb) p.Cb[(size_t)row * p.cpitch + col] = f2bf(v);
      }
    }
  }
}

struct AttnP {
  const unsigned short* kb;
  const unsigned short* tqb;
  const unsigned short* vmb;
  const int* off;
  const int* elist;
  unsigned short* aggb;
  int N, sk, st, sv, nb;
};

__device__ void attn_node(const AttnP& a, int node) {
  int lane = threadIdx.x & 63;
  int e0 = a.off[node], e1 = a.off[node + 1];
  const uint_* tq32 = (const uint_*)(a.tqb + (size_t)node * a.st);
  float tq0[3], tq1[3], m[3], den[3], ac0[3], ac1[3];
#pragma unroll
  for (int j = 0; j < 3; ++j) {
    uint_ u = tq32[lane + 64 * j];
    tq0[j] = blo(u); tq1[j] = bhi(u);
    m[j] = -1e30f; den[j] = 0.f; ac0[j] = 0.f; ac1[j] = 0.f;
  }
  int i = e0;
  for (; i + 2 <= e1; i += 2) {
    int s0 = a.elist[i], s1 = a.elist[i + 1];
    const uint_* k0 = (const uint_*)(a.kb + (size_t)s0 * a.sk);
    const uint_* k1 = (const uint_*)(a.kb + (size_t)s1 * a.sk);
    const uint_* v0 = (const uint_*)(a.vmb + (size_t)s0 * a.sv);
    const uint_* v1 = (const uint_*)(a.vmb + (size_t)s1 * a.sv);
    float pa[3], pb[3]; uint_ va[3], vb[3];
#pragma unroll
    for (int j = 0; j < 3; ++j) {
      uint_ ka = k0[lane + 64 * j], kbu = k1[lane + 64 * j];
      va[j] = v0[lane + 64 * j]; vb[j] = v1[lane + 64 * j];
      pa[j] = blo(ka) * tq0[j] + bhi(ka) * tq1[j];
      pb[j] = blo(kbu) * tq0[j] + bhi(kbu) * tq1[j];
    }
#pragma unroll
    for (int o = 1; o <= 16; o <<= 1)
#pragma unroll
      for (int j = 0; j < 3; ++j) {
        pa[j] += __shfl_xor(pa[j], o);
        pb[j] += __shfl_xor(pb[j], o);
      }
#pragma unroll
    for (int j = 0; j < 3; ++j) {
      float mn = fmaxf(m[j], fmaxf(pa[j], pb[j]));
      float r = __expf(m[j] - mn);
      float p0 = __expf(pa[j] - mn);
      float p1 = __expf(pb[j] - mn);
      den[j] = den[j] * r + p0 + p1;
      ac0[j] = ac0[j] * r + p0 * blo(va[j]) + p1 * blo(vb[j]);
      ac1[j] = ac1[j] * r + p0 * bhi(va[j]) + p1 * bhi(vb[j]);
      m[j] = mn;
    }
  }
  if (i < e1) {
    int s0 = a.elist[i];
    const uint_* k0 = (const uint_*)(a.kb + (size_t)s0 * a.sk);
    const uint_* v0 = (const uint_*)(a.vmb + (size_t)s0 * a.sv);
    float pa[3]; uint_ va[3];
#pragma unroll
    for (int j = 0; j < 3; ++j) {
      uint_ ka = k0[lane + 64 * j];
      va[j] = v0[lane + 64 * j];
      pa[j] = blo(ka) * tq0[j] + bhi(ka) * tq1[j];
    }
#pragma unroll
    for (int o = 1; o <= 16; o <<= 1)
#pragma unroll
      for (int j = 0; j < 3; ++j) pa[j] += __shfl_xor(pa[j], o);
#pragma unroll
    for (int j = 0; j < 3; ++j) {
      float mn = fmaxf(m[j], pa[j]);
      float r = __expf(m[j] - mn);
      float p0 = __expf(pa[j] - mn);
      den[j] = den[j] * r + p0;
      ac0[j] = ac0[j] * r + p0 * blo(va[j]);
      ac1[j] = ac1[j] * r + p0 * bhi(va[j]);
      m[j] = mn;
    }
  }
  uint_* op32 = (uint_*)(a.aggb + (size_t)node * D);
#pragma unroll
  for (int j = 0; j < 3; ++j) {
    float o0 = (e1 > e0) ? ac0[j] / den[j] : 0.f;
    float o1 = (e1 > e0) ? ac1[j] / den[j] : 0.f;
    op32[lane + 64 * j] = (uint_)f2bf(geluf(o0)) | ((uint_)f2bf(geluf(o1)) << 16);
  }
}

// ---------------- standalone fallback kernels (R12 path) ----------------
__global__ __launch_bounds__(256) void gemm_std(GP q0, GP q1, ScatP sc) {
  if (blockIdx.z == 2) {
    int nb = gridDim.x * gridDim.y;
    int flat = blockIdx.y * gridDim.x + blockIdx.x;
    for (long e = (long)flat * 256 + threadIdx.x; e < 2L * sc.E; e += (long)nb * 256) {
      if (e < sc.E) {
        int d = sc.d0[e];
        sc.el0[sc.off0[d] + atomicAdd(&sc.cur0[d], 1)] = sc.s0[e];
      } else {
        long ee = e - sc.E;
        int d = sc.d1[ee];
        sc.el1[sc.off1[d] + atomicAdd(&sc.cur1[d], 1)] = sc.s1[ee];
      }
    }
    return;
  }
  GP p = blockIdx.z ? q1 : q0;
  const int bm = blockIdx.x * 128, bn = blockIdx.y * 128;
  if (bm >= p.M || bn >= p.N) return;
  gemm_tile(p, bm, bn);
}

__global__ void attn_std(AttnP a0, AttnP a1) {
  bool first = (int)blockIdx.x < a0.nb;
  AttnP a = first ? a0 : a1;
  int bx = first ? (int)blockIdx.x : (int)blockIdx.x - a0.nb;
  int node = bx * 4 + (threadIdx.x >> 6);
  if (node < a.N) attn_node(a, node);
}

// ---------------- cooperative mega-kernel ----------------
struct MegaArgs {
  const unsigned short *poolM, *poolC;
  unsigned short *x0b, *x1b, *xn0b, *xn1b;
  unsigned short *projM1, *projC1, *projM2, *projC2;
  unsigned short *aggM, *aggC;
  const unsigned short* wbuf;
  const float *bbuf, *lin_b, *ab, *skip;
  float* out;
  const int *off0, *off1;
  int *el0, *el1, *cur0, *cur1;
  const int *dst_cm, *src_cm, *dst_mc, *src_mc;
  int NM, NC, E;
};

__device__ __forceinline__ void gemm_stage2(const GP& p0, const GP& p1, int mb0, int mb1) {
  int nt0 = mb0 * (p0.N / 128), nt1 = mb1 * (p1.N / 128);
  for (int t = blockIdx.x; t < nt0 + nt1; t += gridDim.x) {
    if (t < nt0) gemm_tile(p0, (t % mb0) * 128, (t / mb0) * 128);
    else { int u = t - nt0; gemm_tile(p1, (u % mb1) * 128, (u / mb1) * 128); }
  }
}

__device__ __forceinline__ void attn_stage2(const AttnP& a0, const AttnP& a1) {
  int wv = threadIdx.x >> 6;
  for (int g = blockIdx.x; g < a0.nb + a1.nb; g += gridDim.x) {
    const AttnP& a = (g < a0.nb) ? a0 : a1;
    int gg = (g < a0.nb) ? g : g - a0.nb;
    int node = gg * 4 + wv;
    if (node < a.N) attn_node(a, node);
  }
}

__global__ __launch_bounds__(256) void mega_kernel(MegaArgs A) {
  coop::grid_group grid = coop::this_grid();
  const int mbM = (A.NM + 127) / 128, mbC = (A.NC + 127) / 128;

  // S1: initial linear (relu) + CSR scatter
  {
    GP p0 = {A.poolM, A.wbuf, A.lin_b, nullptr, A.x0b, nullptr, nullptr, A.NM, D, D, 1};
    GP p1 = {A.poolC, A.wbuf + WSZ, A.lin_b + D, nullptr, A.x1b, nullptr, nullptr, A.NC, D, D, 1};
    int nt0 = mbM * 3, nt1 = mbC * 3;
    const int ST = 256;
    for (int t = blockIdx.x; t < nt0 + nt1 + ST; t += gridDim.x) {
      if (t < nt0) gemm_tile(p0, (t % mbM) * 128, (t / mbM) * 128);
      else if (t < nt0 + nt1) { int u = t - nt0; gemm_tile(p1, (u % mbC) * 128, (u / mbC) * 128); }
      else {
        int u = t - nt0 - nt1;
        for (long e = (long)u * 256 + threadIdx.x; e < 2L * A.E; e += (long)ST * 256) {
          if (e < A.E) {
            int d = A.dst_cm[e];
            A.el0[A.off0[d] + atomicAdd(&A.cur0[d], 1)] = A.src_cm[e];
          } else {
            long ee = e - A.E;
            int d = A.dst_mc[ee];
            A.el1[A.off1[d] + atomicAdd(&A.cur1[d], 1)] = A.src_mc[ee];
          }
        }
      }
    }
  }
  __threadfence();
  grid.sync();
  {
    GP p0 = {A.x0b, A.wbuf + 2 * WSZ, A.bbuf, nullptr, A.projM1, nullptr, nullptr, A.NM, 1152, 1152, 0};
    GP p1 = {A.x1b, A.wbuf + 5 * WSZ, A.bbuf + 1152, nullptr, A.projC1, nullptr, nullptr, A.NC, 1152, 1152, 0};
    gemm_stage2(p0, p1, mbM, mbC);
  }
  __threadfence();
  grid.sync();
  {
    AttnP a0 = {A.projC1, A.projM1 + 384, A.projC1 + 768, A.off0, A.el0, A.aggM, A.NM, 1152, 1152, 1152, (A.NM + 3) / 4};
    AttnP a1 = {A.projM1, A.projC1 + 384, A.projM1 + 768, A.off1, A.el1, A.aggC, A.NC, 1152, 1152, 1152, (A.NC + 3) / 4};
    attn_stage2(a0, a1);
  }
  __threadfence();
  grid.sync();
  {
    GP p0 = {A.aggM, A.wbuf + 11 * WSZ, A.ab, nullptr, A.xn0b, A.x0b, A.skip + 0, A.NM, D, D, 0};
    GP p1 = {A.aggC, A.wbuf + 12 * WSZ, A.ab + D, nullptr, A.xn1b, A.x1b, A.skip + 1, A.NC, D, D, 0};
    gemm_stage2(p0, p1, mbM, mbC);
  }
  __threadfence();
  grid.sync();
  {
    GP p0 = {A.xn0b, A.wbuf + 8 * WSZ, A.bbuf + 2304, nullptr, A.projM2, nullptr, nullptr, A.NM, 384, 384, 0};
    GP p1 = {A.xn1b, A.wbuf + 9 * WSZ, A.bbuf + 2688, nullptr, A.projC2, nullptr, nullptr, A.NC, 768, 768, 0};
    gemm_stage2(p0, p1, mbM, mbC);
  }
  __threadfence();
  grid.sync();
  {
    AttnP a0 = {A.projC2, A.projM2, A.projC2 + 384, A.off0, A.el0, A.aggM, A.NM, 768, 384, 768, (A.NM + 3) / 4};
    int wv = threadIdx.x >> 6;
    for (int g = blockIdx.x; g < a0.nb; g += gridDim.x) {
      int node = g * 4 + wv;
      if (node < a0.N) attn_node(a0, node);
    }
  }
  __threadfence();
  grid.sync();
  {
    GP p0 = {A.aggM, A.wbuf + 13 * WSZ, A.ab + 2 * D, A.out, nullptr, A.xn0b, A.skip + 2, A.NM, D, D, 0};
    int nt0 = mbM * 3;
    for (int t = blockIdx.x; t < nt0; t += gridDim.x)
      gemm_tile(p0, (t % mbM) * 128, (t / mbM) * 128);
  }
}

extern "C" void kernel_launch(void* const* d_in, const int* in_sizes, int n_in,
                              void* d_out, int out_size, void* d_ws, size_t ws_size,
                              hipStream_t stream) {
  const float* tok_msg = (const float*)d_in[0];
  const float* tok_con = (const float*)d_in[1];
  const int* ids_msg = (const int*)d_in[2];
  const int* ids_con = (const int*)d_in[3];
  const int* src_cm = (const int*)d_in[4];
  const int* dst_cm = (const int*)d_in[5];
  const int* src_mc = (const int*)d_in[6];
  const int* dst_mc = (const int*)d_in[7];
  const float* lin_W = (const float*)d_in[8];
  const float* lin_b = (const float*)d_in[9];
  const float* kW = (const float*)d_in[10];
  const float* kb = (const float*)d_in[11];
  const float* qW = (const float*)d_in[12];
  const float* qb = (const float*)d_in[13];
  const float* vW = (const float*)d_in[14];
  const float* vb = (const float*)d_in[15];
  const float* aW = (const float*)d_in[16];
  const float* ab = (const float*)d_in[17];
  const float* a_rel = (const float*)d_in[18];
  const float* m_rel = (const float*)d_in[19];
  const float* p_rel = (const float*)d_in[20];
  const float* skip = (const float*)d_in[21];

  const int NM = in_sizes[2] / L;
  const int NC = in_sizes[3] / L;
  const int E = in_sizes[4];

  char* wsb = (char*)d_ws;
  size_t woff = 0;
  auto alloc = [&](size_t bytes) {
    woff = (woff + 255) & ~(size_t)255;
    void* p = wsb + woff;
    woff += bytes;
    return p;
  };
  const size_t NMe = (size_t)NM * D, NCe = (size_t)NC * D;
  unsigned short* poolM = (unsigned short*)alloc(NMe * 2);
  unsigned short* poolC = (unsigned short*)alloc(NCe * 2);
  unsigned short* x0b = (unsigned short*)alloc(NMe * 2);
  unsigned short* x1b = (unsigned short*)alloc(NCe * 2);
  unsigned short* xn0b = (unsigned short*)alloc(NMe * 2);
  unsigned short* xn1b = (unsigned short*)alloc(NCe * 2);
  unsigned short* projM1 = (unsigned short*)alloc((size_t)NM * 1152 * 2);
  unsigned short* projC1 = (unsigned short*)alloc((size_t)NC * 1152 * 2);
  unsigned short* projM2 = (unsigned short*)alloc((size_t)NM * 384 * 2);
  unsigned short* projC2 = (unsigned short*)alloc((size_t)NC * 768 * 2);
  unsigned short* aggM = (unsigned short*)alloc(NMe * 2);
  unsigned short* aggC = (unsigned short*)alloc(NCe * 2);
  unsigned short* wbuf = (unsigned short*)alloc(14 * WSZ * 2);
  float* bbuf = (float*)alloc(3456 * 4);
  long nz = 2L * NM + 2L * NC;
  int* ibase = (int*)alloc((size_t)(nz + NM + 1 + NC + 1 + 2L * E) * 4);
  int* deg0 = ibase;
  int* cur0 = deg0 + NM;
  int* deg1 = cur0 + NM;
  int* cur1 = deg1 + NC;
  int* off0 = cur1 + NC;
  int* off1 = off0 + NM + 1;
  int* el0 = off1 + NC + 1;
  int* el1 = el0 + E;

  dim3 b256(256);
  const int mbM = (NM + 127) / 128, mbC = (NC + 127) / 128;
  const int mbMax = (mbM > mbC) ? mbM : mbC;

  // 1) zero deg/cur
  zero_int_kernel<<<64, b256, 0, stream>>>(ibase, nz);

  // 2) pool+count with weight/bias prep riding along
  const int NPOOL = NM + NC;
  const int CH = (2 * E + NPOOL - 1) / NPOOL;
  poolprep_kernel<<<NPOOL + 14 * 144 + 7, 512, 0, stream>>>(
      tok_msg, ids_msg, poolM, NM, tok_con, ids_con, poolC, NPOOL,
      dst_cm, dst_mc, deg0, deg1, E, CH,
      lin_W, kW, qW, vW, aW, a_rel, m_rel, p_rel, kb, qb, vb, wbuf, bbuf);

  // 3) scan (tiny)
  scan2_kernel<<<2, 1024, 0, stream>>>(deg0, off0, NM, deg1, off1, NC);

  // 4) cooperative mega-kernel with checked fallback
  MegaArgs ma;
  ma.poolM = poolM; ma.poolC = poolC;
  ma.x0b = x0b; ma.x1b = x1b; ma.xn0b = xn0b; ma.xn1b = xn1b;
  ma.projM1 = projM1; ma.projC1 = projC1; ma.projM2 = projM2; ma.projC2 = projC2;
  ma.aggM = aggM; ma.aggC = aggC;
  ma.wbuf = wbuf; ma.bbuf = bbuf; ma.lin_b = lin_b; ma.ab = ab; ma.skip = skip;
  ma.out = (float*)d_out;
  ma.off0 = off0; ma.off1 = off1; ma.el0 = el0; ma.el1 = el1;
  ma.cur0 = cur0; ma.cur1 = cur1;
  ma.dst_cm = dst_cm; ma.src_cm = src_cm; ma.dst_mc = dst_mc; ma.src_mc = src_mc;
  ma.NM = NM; ma.NC = NC; ma.E = E;
  void* kargs[] = {(void*)&ma};

  hipError_t ce = hipLaunchCooperativeKernel((const void*)mega_kernel, dim3(512), dim3(256),
                                             kargs, 0, stream);
  if (ce != hipSuccess) {
    (void)hipGetLastError();
    ce = hipLaunchCooperativeKernel((const void*)mega_kernel, dim3(256), dim3(256),
                                    kargs, 0, stream);
  }
  if (ce != hipSuccess) {
    (void)hipGetLastError();
    // ---- R12-proven fallback sequence ----
    ScatP scNone = {};
    ScatP scAll = {dst_cm, src_cm, off0, cur0, el0, dst_mc, src_mc, off1, cur1, el1, E};
    {
      GP p0 = {poolM, wbuf, lin_b, nullptr, x0b, nullptr, nullptr, NM, D, D, 1};
      GP p1 = {poolC, wbuf + WSZ, lin_b + D, nullptr, x1b, nullptr, nullptr, NC, D, D, 1};
      gemm_std<<<dim3(mbMax, 3, 3), b256, 0, stream>>>(p0, p1, scAll);
    }
    {
      GP p0 = {x0b, wbuf + 2 * WSZ, bbuf, nullptr, projM1, nullptr, nullptr, NM, 1152, 1152, 0};
      GP p1 = {x1b, wbuf + 5 * WSZ, bbuf + 1152, nullptr, projC1, nullptr, nullptr, NC, 1152, 1152, 0};
      gemm_std<<<dim3(mbMax, 9, 2), b256, 0, stream>>>(p0, p1, scNone);
    }
    {
      AttnP a0 = {projC1, projM1 + 384, projC1 + 768, off0, el0, aggM, NM, 1152, 1152, 1152, (NM + 3) / 4};
      AttnP a1 = {projM1, projC1 + 384, projM1 + 768, off1, el1, aggC, NC, 1152, 1152, 1152, (NC + 3) / 4};
      attn_std<<<(NM + 3) / 4 + (NC + 3) / 4, b256, 0, stream>>>(a0, a1);
    }
    {
      GP p0 = {aggM, wbuf + 11 * WSZ, ab, nullptr, xn0b, x0b, skip + 0, NM, D, D, 0};
      GP p1 = {aggC, wbuf + 12 * WSZ, ab + D, nullptr, xn1b, x1b, skip + 1, NC, D, D, 0};
      gemm_std<<<dim3(mbMax, 3, 2), b256, 0, stream>>>(p0, p1, scNone);
    }
    {
      GP p0 = {xn0b, wbuf + 8 * WSZ, bbuf + 2304, nullptr, projM2, nullptr, nullptr, NM, 384, 384, 0};
      GP p1 = {xn1b, wbuf + 9 * WSZ, bbuf + 2688, nullptr, projC2, nullptr, nullptr, NC, 768, 768, 0};
      gemm_std<<<dim3(mbMax, 6, 2), b256, 0, stream>>>(p0, p1, scNone);
    }
    {
      AttnP a0 = {projC2, projM2, projC2 + 384, off0, el0, aggM, NM, 768, 384, 768, (NM + 3) / 4};
      AttnP a1 = a0;
      attn_std<<<(NM + 3) / 4, b256, 0, stream>>>(a0, a1);
    }
    {
      GP p0 = {aggM, wbuf + 13 * WSZ, ab + 2 * D, (float*)d_out, nullptr, xn0b, skip + 2, NM, D, D, 0};
      GP p1 = p0;
      gemm_std<<<dim3(mbM, 3, 1), b256, 0, stream>>>(p0, p1, scNone);
    }
  }
}

// Round 15
// 628.826 us; speedup vs baseline: 2.5346x; 2.5346x over previous
//
#include <hip/hip_runtime.h>
#include <math.h>

#define H 6
#define DH 64
#define D 384
#define L 16
#define WSZ ((size_t)(D) * (D))
#define RSZ ((size_t)(H) * (DH) * (DH))

typedef __attribute__((ext_vector_type(8))) short short8;
typedef __attribute__((ext_vector_type(4))) float f32x4;
typedef unsigned int uint_;

__device__ __forceinline__ float bf2f(unsigned short u) {
  union { unsigned int i; float f; } x; x.i = ((unsigned int)u) << 16; return x.f;
}
__device__ __forceinline__ unsigned short f2bf(float f) {
  unsigned int x = __float_as_uint(f);
  x = x + 0x7fffu + ((x >> 16) & 1u);
  return (unsigned short)(x >> 16);
}
__device__ __forceinline__ float blo(unsigned int u) { return __uint_as_float(u << 16); }
__device__ __forceinline__ float bhi(unsigned int u) { return __uint_as_float(u & 0xffff0000u); }
__device__ __forceinline__ float geluf(float x) {
  return 0.5f * x * (1.0f + erff(x * 0.70710678118654752f));
}

__global__ void zero_int_kernel(int* p, long n) {
  long i = (long)blockIdx.x * blockDim.x + threadIdx.x;
  long stride = (long)gridDim.x * blockDim.x;
  for (; i < n; i += stride) p[i] = 0;
}

// ---- fused pool+count+prep launch, 512 threads/block, UNION LDS (16.8 KB) ----
__global__ __launch_bounds__(512) void poolprep_kernel(
    const float* __restrict__ tokM, const int* __restrict__ idsM,
    unsigned short* __restrict__ outM, int NM,
    const float* __restrict__ tokC, const int* __restrict__ idsC,
    unsigned short* __restrict__ outC, int NPOOL,
    const int* __restrict__ dc0, const int* __restrict__ dc1,
    int* __restrict__ deg0, int* __restrict__ deg1, int E, int CH,
    const float* __restrict__ lin_W, const float* __restrict__ kW,
    const float* __restrict__ qW, const float* __restrict__ vW,
    const float* __restrict__ aW, const float* __restrict__ a_rel,
    const float* __restrict__ m_rel, const float* __restrict__ p_rel,
    const float* __restrict__ kb, const float* __restrict__ qb,
    const float* __restrict__ vb,
    unsigned short* __restrict__ wbuf, float* __restrict__ bbuf) {
  __shared__ __align__(16) char smem[16768];
  int t = threadIdx.x;
  if ((int)blockIdx.x < NPOOL) {
    {
      int e = blockIdx.x * CH + t;
      if (t < CH && e < 2 * E) {
        if (e < E) atomicAdd(&deg0[dc0[e]], 1);
        else atomicAdd(&deg1[dc1[e - E]], 1);
      }
    }
    float4 (*part)[96] = (float4(*)[96])smem;
    float* wpart = (float*)(smem + 6144);
    int n = blockIdx.x;
    const float* tok; const int* ids; unsigned short* out;
    if (n < NM) { tok = tokM; ids = idsM; out = outM; }
    else { n -= NM; tok = tokC; ids = idsC; out = outC; }
    int rg = t / 96, c4 = t % 96;
    const float4* tp = (const float4*)(tok + (size_t)n * L * D);
    const int* ip = ids + (size_t)n * L;
    int cnt = 0;
#pragma unroll
    for (int l = 0; l < L; ++l) cnt += (ip[l] > 0);
    float4 s = {0.f, 0.f, 0.f, 0.f};
    if (t < 384) {
#pragma unroll
      for (int li = 0; li < 4; ++li) {
        int l = rg + li * 4;
        if (ip[l] > 0) {
          float4 v = tp[l * 96 + c4];
          s.x += v.x; s.y += v.y; s.z += v.z; s.w += v.w;
        }
      }
      part[rg][c4] = s;
    }
    __syncthreads();
    float4 m4 = {0.f, 0.f, 0.f, 0.f};
    float dot = 0.f;
    float inv_cnt = 1.0f / fmaxf((float)cnt, 1e-9f);
    if (t < 96) {
      float4 a = part[0][t], b = part[1][t], c = part[2][t], d2 = part[3][t];
      m4.x = (a.x + b.x + c.x + d2.x) * inv_cnt;
      m4.y = (a.y + b.y + c.y + d2.y) * inv_cnt;
      m4.z = (a.z + b.z + c.z + d2.z) * inv_cnt;
      m4.w = (a.w + b.w + c.w + d2.w) * inv_cnt;
      dot = m4.x * m4.x + m4.y * m4.y + m4.z * m4.z + m4.w * m4.w;
    }
#pragma unroll
    for (int o = 32; o; o >>= 1) dot += __shfl_down(dot, o);
    if ((t & 63) == 0) wpart[t >> 6] = dot;
    __syncthreads();
    float tot = 0.f;
#pragma unroll
    for (int i = 0; i < 8; ++i) tot += wpart[i];
    float inv = 1.0f / fmaxf(sqrtf(tot), 1e-12f);
    if (t < 96) {
      uint2 o;
      o.x = (uint_)f2bf(m4.x * inv) | ((uint_)f2bf(m4.y * inv) << 16);
      o.y = (uint_)f2bf(m4.z * inv) | ((uint_)f2bf(m4.w * inv) << 16);
      ((uint2*)(out + (size_t)n * D))[t] = o;
    }
    return;
  }
  int q = blockIdx.x - NPOOL;
  if (q >= 14 * 144) {
    int i = (q - 14 * 144) * 512 + t;
    if (i >= 3456) return;
    int gemm, col;
    if (i < 1152) { gemm = 0; col = i; }
    else if (i < 2304) { gemm = 1; col = i - 1152; }
    else if (i < 2688) { gemm = 2; col = i - 2304; }
    else { gemm = 3; col = i - 2688; }
    int sec = col / D, j = col % D, h = j >> 6, rr = j & 63;
    float out = 0.f;
    if (gemm == 0) {
      if (sec == 0) out = kb[j];
      else if (sec == 1) {
        const float* R = a_rel + (size_t)h * 4096 + (size_t)rr * 64;
        float s = 0.f; for (int f = 0; f < 64; ++f) s += qb[h * 64 + f] * R[f];
        out = s * p_rel[h] * 0.125f;
      } else {
        const float* Mm = m_rel + RSZ + (size_t)h * 4096;
        float s = 0.f; for (int d = 0; d < 64; ++d) s += vb[h * 64 + d] * Mm[d * 64 + rr]; out = s;
      }
    } else if (gemm == 1) {
      if (sec == 0) out = kb[D + j];
      else if (sec == 1) {
        const float* R = a_rel + RSZ + (size_t)h * 4096 + (size_t)rr * 64;
        float s = 0.f; for (int f = 0; f < 64; ++f) s += qb[D + h * 64 + f] * R[f];
        out = s * p_rel[H + h] * 0.125f;
      } else {
        const float* Mm = m_rel + (size_t)h * 4096;
        float s = 0.f; for (int d = 0; d < 64; ++d) s += vb[D + h * 64 + d] * Mm[d * 64 + rr]; out = s;
      }
    } else if (gemm == 2) {
      const float* R = a_rel + 2 * RSZ + (size_t)h * 4096 + (size_t)rr * 64;
      float s = 0.f; for (int f = 0; f < 64; ++f) s += qb[2 * D + h * 64 + f] * R[f];
      out = s * p_rel[2 * H + h] * 0.125f;
    } else {
      if (sec == 0) out = kb[3 * D + j];
      else {
        const float* Mm = m_rel + 2 * RSZ + (size_t)h * 4096;
        float s = 0.f; for (int d = 0; d < 64; ++d) s += vb[3 * D + h * 64 + d] * Mm[d * 64 + rr]; out = s;
      }
    }
    bbuf[i] = out;
    return;
  }
  int z = q / 144;
  int r = q % 144;
  int px = r % 12, py = r / 12;
  int tx = t & 31, ty16 = t >> 5;
  const float* src; const float* rel = nullptr; const float* prl = nullptr; int type = 0;
  switch (z) {
    case 0: src = lin_W; break;
    case 1: src = lin_W + WSZ; break;
    case 2: src = kW; break;
    case 3: type = 1; src = qW; rel = a_rel; prl = p_rel; break;
    case 4: type = 2; src = vW; rel = m_rel + RSZ; break;
    case 5: src = kW + WSZ; break;
    case 6: type = 1; src = qW + WSZ; rel = a_rel + RSZ; prl = p_rel + H; break;
    case 7: type = 2; src = vW + WSZ; rel = m_rel; break;
    case 8: type = 1; src = qW + 2 * WSZ; rel = a_rel + 2 * RSZ; prl = p_rel + 2 * H; break;
    case 9: src = kW + 3 * WSZ; break;
    case 10: type = 2; src = vW + 3 * WSZ; rel = m_rel + 2 * RSZ; break;
    case 11: src = aW; break;
    case 12: src = aW + WSZ; break;
    default: src = aW + 2 * WSZ; break;
  }
  unsigned short* dst = wbuf + (size_t)z * WSZ;
  int bx = px * 32;
  int by = py * 32;
  if (type == 0) {
    float (*tile)[33] = (float(*)[33])smem;
#pragma unroll
    for (int s = 0; s < 2; ++s) {
      int r2 = ty16 + s * 16;
      tile[r2][tx] = src[(size_t)(bx + r2) * D + by + tx];
    }
    __syncthreads();
#pragma unroll
    for (int s = 0; s < 2; ++s) {
      int ny = ty16 + s * 16;
      dst[(size_t)(by + ny) * D + bx + tx] = f2bf(tile[tx][ny]);
    }
  } else if (type == 1) {
    float (*Wt_)[65] = (float(*)[65])smem;
    float (*Rt)[65] = (float(*)[65])(smem + 8320);
    int h = by >> 6, d0 = by & 63;
    float sc = prl[h] * 0.125f;
#pragma unroll
    for (int i = 0; i < 4; ++i) {
      int idx = t + i * 512;
      int wr = idx >> 6, wc = idx & 63;
      Wt_[wr][wc] = src[(size_t)(bx + wr) * D + h * 64 + wc];
      Rt[wr][wc] = rel[(size_t)h * 4096 + (size_t)(d0 + wr) * 64 + wc];
    }
    __syncthreads();
#pragma unroll
    for (int s = 0; s < 2; ++s) {
      int ny = ty16 + s * 16;
      float acc = 0.f;
#pragma unroll 16
      for (int f = 0; f < 64; ++f) acc += Wt_[tx][f] * Rt[ny][f];
      dst[(size_t)(by + ny) * D + bx + tx] = f2bf(acc * sc);
    }
  } else {
    float (*Wt2)[65] = (float(*)[65])smem;
    float (*Mt)[33] = (float(*)[33])(smem + 8320);
    int h = by >> 6, f0 = by & 63;
#pragma unroll
    for (int i = 0; i < 4; ++i) {
      int idx = t + i * 512;
      int wr = idx >> 6, wc = idx & 63;
      Wt2[wr][wc] = src[(size_t)(bx + wr) * D + h * 64 + wc];
      int dr = idx >> 5, fc = idx & 31;
      Mt[dr][fc] = rel[(size_t)h * 4096 + (size_t)dr * 64 + f0 + fc];
    }
    __syncthreads();
#pragma unroll
    for (int s = 0; s < 2; ++s) {
      int ny = ty16 + s * 16;
      float acc = 0.f;
#pragma unroll 16
      for (int d = 0; d < 64; ++d) acc += Wt2[tx][d] * Mt[d][ny];
      dst[(size_t)(by + ny) * D + bx + tx] = f2bf(acc);
    }
  }
}

// wave-shuffle scan: 3 barriers per 1024-chunk
__global__ void scan2_kernel(const int* __restrict__ deg0, int* __restrict__ off0, int N0,
                             const int* __restrict__ deg1, int* __restrict__ off1, int N1) {
  const int* deg = blockIdx.x ? deg1 : deg0;
  int* off = blockIdx.x ? off1 : off0;
  int N = blockIdx.x ? N1 : N0;
  __shared__ int wsum[16];
  __shared__ int carrySh;
  int tid = threadIdx.x;
  int lane = tid & 63, wid = tid >> 6;
  if (tid == 0) carrySh = 0;
  __syncthreads();
  for (int base = 0; base < N; base += 1024) {
    int i = base + tid;
    int v = (i < N) ? deg[i] : 0;
    int s = v;
#pragma unroll
    for (int o = 1; o < 64; o <<= 1) {
      int t2 = __shfl_up(s, o);
      if (lane >= o) s += t2;
    }
    if (lane == 63) wsum[wid] = s;
    __syncthreads();
    int wpre = 0;
    for (int j = 0; j < wid; ++j) wpre += wsum[j];
    int c = carrySh;
    if (i < N) off[i] = c + wpre + s - v;
    __syncthreads();
    if (tid == 1023) carrySh = c + wpre + s;
    __syncthreads();
  }
  if (tid == 0) off[N] = carrySh;
}

// ---------------- fused per-dst attention, u32-vectorized, 2-edge unrolled ----------------
struct AttnP {
  const unsigned short* kb;
  const unsigned short* tqb;
  const unsigned short* vmb;
  const int* off;
  const int* elist;
  unsigned short* aggb;
  int N, sk, st, sv, nb;
};

__global__ void attn_kernel(AttnP a0, AttnP a1) {
  bool first = (int)blockIdx.x < a0.nb;
  AttnP a = first ? a0 : a1;
  int bx = first ? (int)blockIdx.x : (int)blockIdx.x - a0.nb;
  int node = bx * 4 + (threadIdx.x >> 6);
  int lane = threadIdx.x & 63;
  if (node >= a.N) return;
  int e0 = a.off[node], e1 = a.off[node + 1];
  const uint_* tq32 = (const uint_*)(a.tqb + (size_t)node * a.st);
  float tq0[3], tq1[3], m[3], den[3], ac0[3], ac1[3];
#pragma unroll
  for (int j = 0; j < 3; ++j) {
    uint_ u = tq32[lane + 64 * j];
    tq0[j] = blo(u); tq1[j] = bhi(u);
    m[j] = -1e30f; den[j] = 0.f; ac0[j] = 0.f; ac1[j] = 0.f;
  }
  int i = e0;
  for (; i + 2 <= e1; i += 2) {
    int s0 = a.elist[i], s1 = a.elist[i + 1];
    const uint_* k0 = (const uint_*)(a.kb + (size_t)s0 * a.sk);
    const uint_* k1 = (const uint_*)(a.kb + (size_t)s1 * a.sk);
    const uint_* v0 = (const uint_*)(a.vmb + (size_t)s0 * a.sv);
    const uint_* v1 = (const uint_*)(a.vmb + (size_t)s1 * a.sv);
    float pa[3], pb[3]; uint_ va[3], vb[3];
#pragma unroll
    for (int j = 0; j < 3; ++j) {
      uint_ ka = k0[lane + 64 * j], kbu = k1[lane + 64 * j];
      va[j] = v0[lane + 64 * j]; vb[j] = v1[lane + 64 * j];
      pa[j] = blo(ka) * tq0[j] + bhi(ka) * tq1[j];
      pb[j] = blo(kbu) * tq0[j] + bhi(kbu) * tq1[j];
    }
#pragma unroll
    for (int o = 1; o <= 16; o <<= 1)
#pragma unroll
      for (int j = 0; j < 3; ++j) {
        pa[j] += __shfl_xor(pa[j], o);
        pb[j] += __shfl_xor(pb[j], o);
      }
#pragma unroll
    for (int j = 0; j < 3; ++j) {
      float mn = fmaxf(m[j], fmaxf(pa[j], pb[j]));
      float r = __expf(m[j] - mn);
      float p0 = __expf(pa[j] - mn);
      float p1 = __expf(pb[j] - mn);
      den[j] = den[j] * r + p0 + p1;
      ac0[j] = ac0[j] * r + p0 * blo(va[j]) + p1 * blo(vb[j]);
      ac1[j] = ac1[j] * r + p0 * bhi(va[j]) + p1 * bhi(vb[j]);
      m[j] = mn;
    }
  }
  if (i < e1) {
    int s0 = a.elist[i];
    const uint_* k0 = (const uint_*)(a.kb + (size_t)s0 * a.sk);
    const uint_* v0 = (const uint_*)(a.vmb + (size_t)s0 * a.sv);
    float pa[3]; uint_ va[3];
#pragma unroll
    for (int j = 0; j < 3; ++j) {
      uint_ ka = k0[lane + 64 * j];
      va[j] = v0[lane + 64 * j];
      pa[j] = blo(ka) * tq0[j] + bhi(ka) * tq1[j];
    }
#pragma unroll
    for (int o = 1; o <= 16; o <<= 1)
#pragma unroll
      for (int j = 0; j < 3; ++j) pa[j] += __shfl_xor(pa[j], o);
#pragma unroll
    for (int j = 0; j < 3; ++j) {
      float mn = fmaxf(m[j], pa[j]);
      float r = __expf(m[j] - mn);
      float p0 = __expf(pa[j] - mn);
      den[j] = den[j] * r + p0;
      ac0[j] = ac0[j] * r + p0 * blo(va[j]);
      ac1[j] = ac1[j] * r + p0 * bhi(va[j]);
      m[j] = mn;
    }
  }
  uint_* op32 = (uint_*)(a.aggb + (size_t)node * D);
#pragma unroll
  for (int j = 0; j < 3; ++j) {
    float o0 = (e1 > e0) ? ac0[j] / den[j] : 0.f;
    float o1 = (e1 > e0) ? ac1[j] / den[j] : 0.f;
    op32[lane + 64 * j] = (uint_)f2bf(geluf(o0)) | ((uint_)f2bf(geluf(o1)) << 16);
  }
}

// ---------------- MFMA bf16 GEMM, dual-problem, double-buffered; z==2 slice = scatter ----------------
struct GemmP {
  const unsigned short* A;
  const unsigned short* Wt;
  const float* bias;
  float* Cf;
  unsigned short* Cb;
  const unsigned short* xold;  // bf16 skip input
  const float* skipPtr;
  int M, N, cpitch, relu;
};
struct ScatP {
  const int *d0, *s0, *off0;
  int *cur0, *el0;
  const int *d1, *s1, *off1;
  int *cur1, *el1;
  int E;
};

__global__ __launch_bounds__(256) void gemm_bf16(GemmP q0, GemmP q1, ScatP sc) {
  if (blockIdx.z == 2) {
    int nb = gridDim.x * gridDim.y;
    int flat = blockIdx.y * gridDim.x + blockIdx.x;
    for (long e = (long)flat * 256 + threadIdx.x; e < 2L * sc.E; e += (long)nb * 256) {
      if (e < sc.E) {
        int d = sc.d0[e];
        sc.el0[sc.off0[d] + atomicAdd(&sc.cur0[d], 1)] = sc.s0[e];
      } else {
        long ee = e - sc.E;
        int d = sc.d1[ee];
        sc.el1[sc.off1[d] + atomicAdd(&sc.cur1[d], 1)] = sc.s1[ee];
      }
    }
    return;
  }
  GemmP p = blockIdx.z ? q1 : q0;
  const int bm = blockIdx.x * 128, bn = blockIdx.y * 128;
  if (bm >= p.M || bn >= p.N) return;
  __shared__ __align__(16) unsigned short As[2][128 * 64];
  __shared__ __align__(16) unsigned short Bs[2][128 * 64];
  const int tid = threadIdx.x;
  const int w = tid >> 6, lane = tid & 63;

  auto stage = [&](int t, int buf) {
#pragma unroll
    for (int i = 0; i < 4; ++i) {
      int cid = (w * 4 + i) * 64 + lane;
      int row = cid >> 3;
      int cg = (cid & 7) ^ (row & 7);
      int grow = bm + row;
      if (grow >= p.M) grow = p.M - 1;
      const unsigned short* gp = p.A + (size_t)grow * D + t * 64 + cg * 8;
      __builtin_amdgcn_global_load_lds((const __attribute__((address_space(1))) void*)gp,
                                       (__attribute__((address_space(3))) void*)&As[buf][(w * 4 + i) * 512],
                                       16, 0, 0);
    }
#pragma unroll
    for (int i = 0; i < 4; ++i) {
      int cid = (w * 4 + i) * 64 + lane;
      int row = cid >> 3;
      int cg = (cid & 7) ^ (row & 7);
      const unsigned short* gp = p.Wt + (size_t)(bn + row) * D + t * 64 + cg * 8;
      __builtin_amdgcn_global_load_lds((const __attribute__((address_space(1))) void*)gp,
                                       (__attribute__((address_space(3))) void*)&Bs[buf][(w * 4 + i) * 512],
                                       16, 0, 0);
    }
  };

  stage(0, 0);
  __syncthreads();

  const int wr = w >> 1, wc = w & 1;
  const int la = lane & 15, hi = lane >> 4;
  f32x4 acc[4][4] = {};

  for (int t = 0; t < 6; ++t) {
    if (t < 5) stage(t + 1, (t + 1) & 1);
    const unsigned short* Ab = As[t & 1];
    const unsigned short* Bb = Bs[t & 1];
#pragma unroll
    for (int ks = 0; ks < 2; ++ks) {
      int c = ks * 4 + hi;
      short8 af[4], bfr[4];
#pragma unroll
      for (int mi = 0; mi < 4; ++mi) {
        int row = wr * 64 + mi * 16 + la;
        af[mi] = *(const short8*)&Ab[row * 64 + ((c ^ (row & 7)) * 8)];
      }
#pragma unroll
      for (int n = 0; n < 4; ++n) {
        int col = wc * 64 + n * 16 + la;
        bfr[n] = *(const short8*)&Bb[col * 64 + ((c ^ (col & 7)) * 8)];
      }
#pragma unroll
      for (int mi = 0; mi < 4; ++mi)
#pragma unroll
        for (int n = 0; n < 4; ++n)
          acc[mi][n] = __builtin_amdgcn_mfma_f32_16x16x32_bf16(af[mi], bfr[n], acc[mi][n], 0, 0, 0);
    }
    __syncthreads();
  }

  float sa = 0.f;
  if (p.xold) sa = 1.0f / (1.0f + __expf(-*p.skipPtr));
#pragma unroll
  for (int mi = 0; mi < 4; ++mi) {
#pragma unroll
    for (int n = 0; n < 4; ++n) {
#pragma unroll
      for (int r = 0; r < 4; ++r) {
        int row = bm + wr * 64 + mi * 16 + hi * 4 + r;
        int col = bn + wc * 64 + n * 16 + la;
        if (row >= p.M) continue;
        float v = acc[mi][n][r] + p.bias[col];
        if (p.relu) v = fmaxf(v, 0.f);
        if (p.xold) v = sa * v + (1.0f - sa) * bf2f(p.xold[(size_t)row * D + col]);
        if (p.Cf) p.Cf[(size_t)row * p.cpitch + col] = v;
        if (p.Cb) p.Cb[(size_t)row * p.cpitch + col] = f2bf(v);
      }
    }
  }
}

extern "C" void kernel_launch(void* const* d_in, const int* in_sizes, int n_in,
                              void* d_out, int out_size, void* d_ws, size_t ws_size,
                              hipStream_t stream) {
  const float* tok_msg = (const float*)d_in[0];
  const float* tok_con = (const float*)d_in[1];
  const int* ids_msg = (const int*)d_in[2];
  const int* ids_con = (const int*)d_in[3];
  const int* src_cm = (const int*)d_in[4];
  const int* dst_cm = (const int*)d_in[5];
  const int* src_mc = (const int*)d_in[6];
  const int* dst_mc = (const int*)d_in[7];
  const float* lin_W = (const float*)d_in[8];
  const float* lin_b = (const float*)d_in[9];
  const float* kW = (const float*)d_in[10];
  const float* kb = (const float*)d_in[11];
  const float* qW = (const float*)d_in[12];
  const float* qb = (const float*)d_in[13];
  const float* vW = (const float*)d_in[14];
  const float* vb = (const float*)d_in[15];
  const float* aW = (const float*)d_in[16];
  const float* ab = (const float*)d_in[17];
  const float* a_rel = (const float*)d_in[18];
  const float* m_rel = (const float*)d_in[19];
  const float* p_rel = (const float*)d_in[20];
  const float* skip = (const float*)d_in[21];

  const int NM = in_sizes[2] / L;
  const int NC = in_sizes[3] / L;
  const int E = in_sizes[4];

  char* wsb = (char*)d_ws;
  size_t woff = 0;
  auto alloc = [&](size_t bytes) {
    woff = (woff + 255) & ~(size_t)255;
    void* p = wsb + woff;
    woff += bytes;
    return p;
  };
  const size_t NMe = (size_t)NM * D, NCe = (size_t)NC * D;
  unsigned short* poolM = (unsigned short*)alloc(NMe * 2);
  unsigned short* poolC = (unsigned short*)alloc(NCe * 2);
  unsigned short* x0b = (unsigned short*)alloc(NMe * 2);
  unsigned short* x1b = (unsigned short*)alloc(NCe * 2);
  unsigned short* xn0b = (unsigned short*)alloc(NMe * 2);
  unsigned short* xn1b = (unsigned short*)alloc(NCe * 2);
  unsigned short* projM1 = (unsigned short*)alloc((size_t)NM * 1152 * 2);
  unsigned short* projC1 = (unsigned short*)alloc((size_t)NC * 1152 * 2);
  unsigned short* projM2 = (unsigned short*)alloc((size_t)NM * 384 * 2);
  unsigned short* projC2 = (unsigned short*)alloc((size_t)NC * 768 * 2);
  unsigned short* aggM = (unsigned short*)alloc(NMe * 2);
  unsigned short* aggC = (unsigned short*)alloc(NCe * 2);
  unsigned short* wbuf = (unsigned short*)alloc(14 * WSZ * 2);
  float* bbuf = (float*)alloc(3456 * 4);
  // CSR ints: ONE contiguous block, hand-sliced (no per-array padding)
  long nz = 2L * NM + 2L * NC;  // deg0|cur0|deg1|cur1 prefix zeroed every launch
  int* ibase = (int*)alloc((size_t)(nz + NM + 1 + NC + 1 + 2L * E) * 4);
  int* deg0 = ibase;
  int* cur0 = deg0 + NM;
  int* deg1 = cur0 + NM;
  int* cur1 = deg1 + NC;
  int* off0 = cur1 + NC;
  int* off1 = off0 + NM + 1;
  int* el0 = off1 + NC + 1;
  int* el1 = el0 + E;

  dim3 b256(256);
  const int mbM = (NM + 127) / 128, mbC = (NC + 127) / 128;
  const int mbMax = (mbM > mbC) ? mbM : mbC;
  ScatP scNone = {};
  ScatP scAll = {dst_cm, src_cm, off0, cur0, el0, dst_mc, src_mc, off1, cur1, el1, E};

  // 1) zero deg/cur
  zero_int_kernel<<<64, b256, 0, stream>>>(ibase, nz);

  // 2) pool+count (HBM-bound) with weight/bias prep riding along (union LDS -> full occupancy)
  const int NPOOL = NM + NC;
  const int CH = (2 * E + NPOOL - 1) / NPOOL;
  poolprep_kernel<<<NPOOL + 14 * 144 + 7, 512, 0, stream>>>(
      tok_msg, ids_msg, poolM, NM, tok_con, ids_con, poolC, NPOOL,
      dst_cm, dst_mc, deg0, deg1, E, CH,
      lin_W, kW, qW, vW, aW, a_rel, m_rel, p_rel, kb, qb, vb, wbuf, bbuf);

  // 3) scan (tiny)
  scan2_kernel<<<2, 1024, 0, stream>>>(deg0, off0, NM, deg1, off1, NC);

  // 4) initial linear (relu) || CSR scatter (z==2)
  {
    GemmP p0 = {poolM, wbuf, lin_b, nullptr, x0b, nullptr, nullptr, NM, D, D, 1};
    GemmP p1 = {poolC, wbuf + WSZ, lin_b + D, nullptr, x1b, nullptr, nullptr, NC, D, D, 1};
    gemm_bf16<<<dim3(mbMax, 3, 3), b256, 0, stream>>>(p0, p1, scAll);
  }
  // 5) layer 1: fused k|tq|vm projections, both node types
  {
    GemmP p0 = {x0b, wbuf + 2 * WSZ, bbuf, nullptr, projM1, nullptr, nullptr, NM, 1152, 1152, 0};
    GemmP p1 = {x1b, wbuf + 5 * WSZ, bbuf + 1152, nullptr, projC1, nullptr, nullptr, NC, 1152, 1152, 0};
    gemm_bf16<<<dim3(mbMax, 9, 2), b256, 0, stream>>>(p0, p1, scNone);
  }
  // 6) layer 1 attention, both edge types
  {
    AttnP a0 = {projC1, projM1 + 384, projC1 + 768, off0, el0, aggM, NM, 1152, 1152, 1152, (NM + 3) / 4};
    AttnP a1 = {projM1, projC1 + 384, projM1 + 768, off1, el1, aggC, NC, 1152, 1152, 1152, (NC + 3) / 4};
    attn_kernel<<<(NM + 3) / 4 + (NC + 3) / 4, b256, 0, stream>>>(a0, a1);
  }
  // 7) layer 1 a-proj + skip blend (bf16 xold)
  {
    GemmP p0 = {aggM, wbuf + 11 * WSZ, ab, nullptr, xn0b, x0b, skip + 0, NM, D, D, 0};
    GemmP p1 = {aggC, wbuf + 12 * WSZ, ab + D, nullptr, xn1b, x1b, skip + 1, NC, D, D, 0};
    gemm_bf16<<<dim3(mbMax, 3, 2), b256, 0, stream>>>(p0, p1, scNone);
  }
  // 8) layer 2 projections (M: tq only, N=384; C: k|vm, N=768)
  {
    GemmP p0 = {xn0b, wbuf + 8 * WSZ, bbuf + 2304, nullptr, projM2, nullptr, nullptr, NM, 384, 384, 0};
    GemmP p1 = {xn1b, wbuf + 9 * WSZ, bbuf + 2688, nullptr, projC2, nullptr, nullptr, NC, 768, 768, 0};
    gemm_bf16<<<dim3(mbMax, 6, 2), b256, 0, stream>>>(p0, p1, scNone);
  }
  // 9) layer 2 attention (edge type 0 only)
  {
    AttnP a0 = {projC2, projM2, projC2 + 384, off0, el0, aggM, NM, 768, 384, 768, (NM + 3) / 4};
    AttnP a1 = a0;
    attn_kernel<<<(NM + 3) / 4, b256, 0, stream>>>(a0, a1);
  }
  // 10) layer 2 a-proj -> d_out (f32), bf16 xold
  {
    GemmP p0 = {aggM, wbuf + 13 * WSZ, ab + 2 * D, (float*)d_out, nullptr, xn0b, skip + 2, NM, D, D, 0};
    GemmP p1 = p0;
    gemm_bf16<<<dim3(mbM, 3, 1), b256, 0, stream>>>(p0, p1, scNone);
  }
}